// Round 8
// baseline (461.531 us; speedup 1.0000x reference)
//
#include <hip/hip_runtime.h>
#include <math.h>

#define F_IN 128
#define H_DIM 64
#define C_OUT 40
#define NBK 391          // ceil(100000/256) coarse buckets, 256 nodes each
#define CHUNK 4096       // edges per binscatter block

typedef _Float16 h8 __attribute__((ext_vector_type(8)));  // 16B = 8 fp16 features
typedef float nf4 __attribute__((ext_vector_type(4)));    // native float4 (nt-load-able)

// ---------------- CSR build: two-level LDS counting sort ----------------

__global__ void __launch_bounds__(256) bhist_kernel(const int* __restrict__ dst,
                                                    int* __restrict__ bhist, int E) {
    __shared__ int lh[512];
    int tid = threadIdx.x;
    lh[tid] = 0; lh[tid + 256] = 0;
    __syncthreads();
    int stride = gridDim.x * 256;
    for (int e = blockIdx.x * 256 + tid; e < E; e += stride) {
        int d = __builtin_nontemporal_load(&dst[e]);
        atomicAdd(&lh[d >> 8], 1);
    }
    __syncthreads();
    if (lh[tid]) atomicAdd(&bhist[tid], lh[tid]);
    if (lh[tid + 256]) atomicAdd(&bhist[tid + 256], lh[tid + 256]);
}

__global__ void __launch_bounds__(512) bscan_kernel(const int* __restrict__ bhist,
                                                    int* __restrict__ bbase,
                                                    int* __restrict__ bcursor, int E) {
    __shared__ int sa[512], sb[512];
    int t = threadIdx.x;
    int v = (t < NBK) ? bhist[t] : 0;
    sa[t] = v;
    __syncthreads();
    int* pa = sa; int* pb = sb;
#pragma unroll
    for (int off = 1; off < 512; off <<= 1) {
        pb[t] = pa[t] + ((t >= off) ? pa[t - off] : 0);
        __syncthreads();
        int* tmp = pa; pa = pb; pb = tmp;
    }
    if (t < NBK) {
        int excl = pa[t] - v;
        bbase[t] = excl;
        bcursor[t] = excl;
    }
    if (t == 0) bbase[NBK] = E;
}

__global__ void __launch_bounds__(256) binscatter_kernel(const int* __restrict__ src,
                                                         const int* __restrict__ dst,
                                                         int* __restrict__ bcursor,
                                                         int2* __restrict__ pairs, int E) {
    __shared__ int2 sp[CHUNK];
    __shared__ unsigned short sbof[CHUNK];
    __shared__ int hist[512];
    __shared__ int scanA[512], scanB[512];
    __shared__ int cur[512];
    __shared__ int gbase[512];
    int tid = threadIdx.x;
    int e0 = blockIdx.x * CHUNK;
    int cnt = min(CHUNK, E - e0);

    int dv[CHUNK / 256], sv[CHUNK / 256];
#pragma unroll
    for (int i = 0; i < CHUNK / 256; i++) {
        int idx = tid + i * 256;
        if (idx < cnt) {
            dv[i] = __builtin_nontemporal_load(&dst[e0 + idx]);
            sv[i] = __builtin_nontemporal_load(&src[e0 + idx]);
        }
    }
    hist[tid] = 0; hist[tid + 256] = 0;
    __syncthreads();
#pragma unroll
    for (int i = 0; i < CHUNK / 256; i++) {
        int idx = tid + i * 256;
        if (idx < cnt) atomicAdd(&hist[dv[i] >> 8], 1);
    }
    __syncthreads();
    scanA[tid] = hist[tid]; scanA[tid + 256] = hist[tid + 256];
    __syncthreads();
    int* pa = scanA; int* pb = scanB;
#pragma unroll
    for (int off = 1; off < 512; off <<= 1) {
        pb[tid] = pa[tid] + ((tid >= off) ? pa[tid - off] : 0);
        int t1 = tid + 256;
        pb[t1] = pa[t1] + ((t1 >= off) ? pa[t1 - off] : 0);
        __syncthreads();
        int* tmp = pa; pa = pb; pb = tmp;
    }
    cur[tid] = pa[tid] - hist[tid];
    cur[tid + 256] = pa[tid + 256] - hist[tid + 256];
    __syncthreads();
#pragma unroll
    for (int i = 0; i < CHUNK / 256; i++) {
        int idx = tid + i * 256;
        if (idx < cnt) {
            int b = dv[i] >> 8;
            int lp = atomicAdd(&cur[b], 1);
            sp[lp] = make_int2(dv[i], sv[i]);
            sbof[lp] = (unsigned short)b;
        }
    }
    {
        int c0 = hist[tid];
        gbase[tid] = c0 ? atomicAdd(&bcursor[tid], c0) : 0;
        int c1 = hist[tid + 256];
        gbase[tid + 256] = c1 ? atomicAdd(&bcursor[tid + 256], c1) : 0;
    }
    __syncthreads();
    for (int i = tid; i < cnt; i += 256) {
        int b = sbof[i];
        int off_in_b = i - (pa[b] - hist[b]);
        pairs[gbase[b] + off_in_b] = sp[i];
    }
}

__global__ void __launch_bounds__(256) bucketsort_kernel(const int2* __restrict__ pairs,
                                                         const int* __restrict__ bbase,
                                                         int* __restrict__ rowptr,
                                                         int* __restrict__ ssrc, int N, int E) {
    __shared__ int hist[256], scanA[256], scanB[256], cur[256];
    int b = blockIdx.x;
    int tid = threadIdx.x;
    int e0 = bbase[b], e1 = bbase[b + 1];
    hist[tid] = 0;
    __syncthreads();
    for (int e = e0 + tid; e < e1; e += 256) {
        int2 p = pairs[e];
        atomicAdd(&hist[p.x & 255], 1);
    }
    __syncthreads();
    scanA[tid] = hist[tid];
    __syncthreads();
    int* pa = scanA; int* pb = scanB;
#pragma unroll
    for (int off = 1; off < 256; off <<= 1) {
        pb[tid] = pa[tid] + ((tid >= off) ? pa[tid - off] : 0);
        __syncthreads();
        int* tmp = pa; pa = pb; pb = tmp;
    }
    int excl = pa[tid] - hist[tid];
    int node = (b << 8) + tid;
    if (node < N) rowptr[node] = e0 + excl;
    if (b == NBK - 1 && tid == 0) rowptr[N] = E;
    cur[tid] = e0 + excl;
    __syncthreads();
    for (int e = e0 + tid; e < e1; e += 256) {
        int2 p = pairs[e];
        int pos = atomicAdd(&cur[p.x & 255], 1);
        ssrc[pos] = p.y;
    }
}

// ---------------- lin1: LDS-staged x tile, 32 rows/block, fp16 h out ----------------
__global__ void __launch_bounds__(256) lin1_kernel(
        const float* __restrict__ x, const float* __restrict__ W1,
        const float* __restrict__ b1, _Float16* __restrict__ hout,
        float* __restrict__ rn, int n) {
    __shared__ float sx[32 * F_IN];  // 16 KB
    int tid = threadIdx.x;
    int r0 = blockIdx.x * 32;
    int rows = min(32, n - r0);

    {
        const nf4* xg = (const nf4*)(x + (size_t)r0 * F_IN);
        nf4* sx4 = (nf4*)sx;
        int tot = rows * (F_IN / 4);
        for (int i = tid; i < tot; i += 256) sx4[i] = __builtin_nontemporal_load(&xg[i]);
    }
    __syncthreads();

    int wave = tid >> 6, lane = tid & 63;
    int rbase = wave * 8;
    float bl = b1[lane];
    float acc[8];
#pragma unroll
    for (int j = 0; j < 8; j++) acc[j] = bl;

    const float4* sx4 = (const float4*)sx;
#pragma unroll 2
    for (int k = 0; k < F_IN; k += 4) {
        float w0 = W1[(k + 0) * H_DIM + lane];
        float w1 = W1[(k + 1) * H_DIM + lane];
        float w2 = W1[(k + 2) * H_DIM + lane];
        float w3 = W1[(k + 3) * H_DIM + lane];
#pragma unroll
        for (int j = 0; j < 8; j++) {
            float4 xv = sx4[(rbase + j) * (F_IN / 4) + (k >> 2)];
            acc[j] = fmaf(xv.x, w0, acc[j]);
            acc[j] = fmaf(xv.y, w1, acc[j]);
            acc[j] = fmaf(xv.z, w2, acc[j]);
            acc[j] = fmaf(xv.w, w3, acc[j]);
        }
    }

#pragma unroll
    for (int j = 0; j < 8; j++) {
        int r = rbase + j;
        if (r >= rows) break;
        float a = fmaxf(acc[j], 0.0f);
        hout[(size_t)(r0 + r) * H_DIM + lane] = (_Float16)a;
        float ss = a * a;
#pragma unroll
        for (int k = 1; k < 64; k <<= 1) ss += __shfl_xor(ss, k, 64);
        if (lane == 0) rn[r0 + r] = 1.0f / fmaxf(sqrtf(ss), 1e-12f);
    }
}

// ---- AGNN layer: wave/dst, 8 lanes/edge; batched load-all-then-compute (deg<=32) ----
__global__ void __launch_bounds__(256) agnn_kernel(
        const h8* __restrict__ h, const float* __restrict__ rnorm,
        const int* __restrict__ rowptr, const int* __restrict__ ssrc,
        h8* __restrict__ hout, float* __restrict__ rnout, int n) {
    int wid = (blockIdx.x * blockDim.x + threadIdx.x) >> 6;
    int t = threadIdx.x & 63;
    if (wid >= n) return;
    int g = t >> 3;    // edge group 0..7
    int sub = t & 7;   // feature chunk (8 halves = 16B)

    h8 hd16 = h[(size_t)wid * 8 + sub];
    float hd[8];
#pragma unroll
    for (int i = 0; i < 8; i++) hd[i] = (float)hd16[i];
    float rni = rnorm[wid];

    float dself = 0.0f;
#pragma unroll
    for (int i = 0; i < 8; i++) dself = fmaf(hd[i], hd[i], dself);
#pragma unroll
    for (int k = 1; k < 8; k <<= 1) dself += __shfl_xor(dself, k, 64);
    float wself = __expf(dself * rni * rni);

    float acc[8];
    float sw = (g == 0) ? wself : 0.0f;
#pragma unroll
    for (int i = 0; i < 8; i++) acc[i] = (g == 0) ? wself * hd[i] : 0.0f;

    int e0 = rowptr[wid];
    int end = rowptr[wid + 1];
    int deg = end - e0;

    // batched phase: group g owns edge positions g, g+8, g+16, g+24.
    // ALL gathers issued before any compute -> 32 row-gathers in flight per wave.
    {
        int nb = min(deg, 32);
        int idx[4];
        bool val[4];
#pragma unroll
        for (int j = 0; j < 4; j++) {
            int p = g + 8 * j;
            val[j] = p < nb;
            idx[j] = ssrc[val[j] ? (e0 + p) : 0];  // clamp: safe address, masked later
        }
        h8 row[4];
#pragma unroll
        for (int j = 0; j < 4; j++) row[j] = h[(size_t)idx[j] * 8 + sub];
        float rnv[4];
#pragma unroll
        for (int j = 0; j < 4; j++) rnv[j] = rnorm[idx[j]];

        float d[4];
#pragma unroll
        for (int j = 0; j < 4; j++) {
            float dd = 0.0f;
#pragma unroll
            for (int i = 0; i < 8; i++) dd = fmaf((float)row[j][i], hd[i], dd);
            d[j] = dd;
        }
#pragma unroll
        for (int k = 1; k < 8; k <<= 1) {
#pragma unroll
            for (int j = 0; j < 4; j++) d[j] += __shfl_xor(d[j], k, 64);
        }
#pragma unroll
        for (int j = 0; j < 4; j++) {
            float w = val[j] ? __expf(d[j] * rni * rnv[j]) : 0.0f;
#pragma unroll
            for (int i = 0; i < 8; i++) acc[i] = fmaf(w, (float)row[j][i], acc[i]);
            sw += w;
        }
    }

    // overflow (deg > 32, ~1e-4 of nodes): simple per-group loop
    for (int e = e0 + 32 + g; e < end; e += 8) {
        int s0 = ssrc[e];
        h8 a16 = h[(size_t)s0 * 8 + sub];
        float rn0 = rnorm[s0];
        float d0 = 0.0f;
#pragma unroll
        for (int i = 0; i < 8; i++) d0 = fmaf((float)a16[i], hd[i], d0);
#pragma unroll
        for (int k = 1; k < 8; k <<= 1) d0 += __shfl_xor(d0, k, 64);
        float w0 = __expf(d0 * rni * rn0);
#pragma unroll
        for (int i = 0; i < 8; i++) acc[i] = fmaf(w0, (float)a16[i], acc[i]);
        sw += w0;
    }

#pragma unroll
    for (int k = 8; k < 64; k <<= 1) {
#pragma unroll
        for (int i = 0; i < 8; i++) acc[i] += __shfl_xor(acc[i], k, 64);
        sw += __shfl_xor(sw, k, 64);
    }
    float inv = 1.0f / sw;
    float o[8];
#pragma unroll
    for (int i = 0; i < 8; i++) o[i] = acc[i] * inv;
    if (g == 0) {
        h8 oh;
#pragma unroll
        for (int i = 0; i < 8; i++) oh[i] = (_Float16)o[i];
        hout[(size_t)wid * 8 + sub] = oh;
    }
    float ss = 0.0f;
#pragma unroll
    for (int i = 0; i < 8; i++) ss = fmaf(o[i], o[i], ss);
#pragma unroll
    for (int k = 1; k < 8; k <<= 1) ss += __shfl_xor(ss, k, 64);
    if (t == 0) rnout[wid] = 1.0f / fmaxf(sqrtf(ss), 1e-12f);
}

// ---------------- lin2 + log_softmax: fp16 input, LDS-staged, 32 rows/block ----------------
__global__ void __launch_bounds__(256) lin2_kernel(
        const h8* __restrict__ h, const float* __restrict__ W2,
        const float* __restrict__ b2, float* __restrict__ out, int n) {
    __shared__ h8 sh[32 * 8];  // 4 KB
    int tid = threadIdx.x;
    int r0 = blockIdx.x * 32;
    int rows = min(32, n - r0);

    {
        const uint4* hg = (const uint4*)(h + (size_t)r0 * 8);
        uint4* sh4 = (uint4*)sh;
        int tot = rows * 8;
        for (int i = tid; i < tot; i += 256) sh4[i] = hg[i];
    }
    __syncthreads();

    int wave = tid >> 6, lane = tid & 63;
    int rbase = wave * 8;

    float acc[8];
    if (lane < C_OUT) {
        float bl = b2[lane];
#pragma unroll
        for (int j = 0; j < 8; j++) acc[j] = bl;
#pragma unroll 2
        for (int k = 0; k < H_DIM; k += 8) {
            float w[8];
#pragma unroll
            for (int i = 0; i < 8; i++) w[i] = W2[(k + i) * C_OUT + lane];
#pragma unroll
            for (int j = 0; j < 8; j++) {
                h8 hv = sh[(rbase + j) * 8 + (k >> 3)];
#pragma unroll
                for (int i = 0; i < 8; i++) acc[j] = fmaf((float)hv[i], w[i], acc[j]);
            }
        }
    } else {
#pragma unroll
        for (int j = 0; j < 8; j++) acc[j] = -INFINITY;
    }

#pragma unroll
    for (int j = 0; j < 8; j++) {
        int r = rbase + j;
        if (r >= rows) break;
        float m = acc[j];
#pragma unroll
        for (int k = 1; k < 64; k <<= 1) m = fmaxf(m, __shfl_xor(m, k, 64));
        float e = (lane < C_OUT) ? __expf(acc[j] - m) : 0.0f;
        float s = e;
#pragma unroll
        for (int k = 1; k < 64; k <<= 1) s += __shfl_xor(s, k, 64);
        if (lane < C_OUT) out[(size_t)(r0 + r) * C_OUT + lane] = acc[j] - m - logf(s);
    }
}

// ---------------- launch ----------------

extern "C" void kernel_launch(void* const* d_in, const int* in_sizes, int n_in,
                              void* d_out, int out_size, void* d_ws, size_t ws_size,
                              hipStream_t stream) {
    const float* x = (const float*)d_in[0];
    const float* W1 = (const float*)d_in[1];
    const float* b1 = (const float*)d_in[2];
    const float* W2 = (const float*)d_in[3];
    const float* b2 = (const float*)d_in[4];
    const int* ei = (const int*)d_in[5];

    const int N = in_sizes[0] / F_IN;      // 100000
    const int E = in_sizes[5] / 2;         // 1600000
    const int* src = ei;
    const int* dst = ei + E;

    char* w = (char*)d_ws;
    auto carve = [&](size_t bytes) {
        char* p = w;
        w += (bytes + 255) & ~(size_t)255;
        return p;
    };
    _Float16* g1 = (_Float16*)carve((size_t)N * H_DIM * 2);
    _Float16* g2 = (_Float16*)carve((size_t)N * H_DIM * 2);   // aliased as pairs during CSR build
    float* rn1 = (float*)carve((size_t)N * 4);
    float* rn2 = (float*)carve((size_t)N * 4);
    int* rowptr = (int*)carve((size_t)(N + 1) * 4);
    int* bhist = (int*)carve(512 * 4);
    int* bbase = (int*)carve(512 * 4);
    int* bcursor = (int*)carve(512 * 4);
    int* ssrc = (int*)carve((size_t)E * 4);
    int2* pairs = (int2*)g2;   // 12.8 MB alias: pairs dead before agnn layer 1 writes g2

    // CSR build: two-level LDS counting sort (all writes structurally coalesced)
    (void)hipMemsetAsync(bhist, 0, 512 * 4, stream);
    bhist_kernel<<<512, 256, 0, stream>>>(dst, bhist, E);
    bscan_kernel<<<1, 512, 0, stream>>>(bhist, bbase, bcursor, E);
    binscatter_kernel<<<(E + CHUNK - 1) / CHUNK, 256, 0, stream>>>(src, dst, bcursor, pairs, E);
    bucketsort_kernel<<<NBK, 256, 0, stream>>>(pairs, bbase, rowptr, ssrc, N, E);

    // lin1 (+rnorm), fp16 h out
    lin1_kernel<<<(N + 31) / 32, 256, 0, stream>>>(x, W1, b1, g1, rn1, N);

    // 4 AGNN layers, ping-pong on fp16 h
    {
        int blocks = (N * 64 + 255) / 256;
        agnn_kernel<<<blocks, 256, 0, stream>>>((const h8*)g1, rn1, rowptr, ssrc, (h8*)g2, rn2, N);
        agnn_kernel<<<blocks, 256, 0, stream>>>((const h8*)g2, rn2, rowptr, ssrc, (h8*)g1, rn1, N);
        agnn_kernel<<<blocks, 256, 0, stream>>>((const h8*)g1, rn1, rowptr, ssrc, (h8*)g2, rn2, N);
        agnn_kernel<<<blocks, 256, 0, stream>>>((const h8*)g2, rn2, rowptr, ssrc, (h8*)g1, rn1, N);
    }

    // lin2 + log_softmax
    lin2_kernel<<<(N + 31) / 32, 256, 0, stream>>>((const h8*)g1, W2, b2, (float*)d_out, N);
}

// Round 9
// 439.963 us; speedup vs baseline: 1.0490x; 1.0490x over previous
//
#include <hip/hip_runtime.h>
#include <math.h>

#define F_IN 128
#define H_DIM 64
#define C_OUT 40
#define NBK 391          // ceil(100000/256) coarse buckets, 256 nodes each
#define CHUNK 4096       // edges per binscatter block

typedef _Float16 h8 __attribute__((ext_vector_type(8)));   // 16B = 8 fp16 features
typedef _Float16 half2t __attribute__((ext_vector_type(2)));
typedef float nf4 __attribute__((ext_vector_type(4)));     // native float4 (nt-load-able)

union H8 {
    h8 v;
    half2t p[4];
};

__device__ __forceinline__ float dot8(const H8& a, const H8& b) {
    float d = __builtin_amdgcn_fdot2(a.p[0], b.p[0], 0.0f, false);
    d = __builtin_amdgcn_fdot2(a.p[1], b.p[1], d, false);
    d = __builtin_amdgcn_fdot2(a.p[2], b.p[2], d, false);
    d = __builtin_amdgcn_fdot2(a.p[3], b.p[3], d, false);
    return d;
}

// ---------------- CSR build: two-level LDS counting sort ----------------

__global__ void __launch_bounds__(256) bhist_kernel(const int* __restrict__ dst,
                                                    int* __restrict__ bhist, int E) {
    __shared__ int lh[512];
    int tid = threadIdx.x;
    lh[tid] = 0; lh[tid + 256] = 0;
    __syncthreads();
    int stride = gridDim.x * 256;
    for (int e = blockIdx.x * 256 + tid; e < E; e += stride) {
        int d = __builtin_nontemporal_load(&dst[e]);
        atomicAdd(&lh[d >> 8], 1);
    }
    __syncthreads();
    if (lh[tid]) atomicAdd(&bhist[tid], lh[tid]);
    if (lh[tid + 256]) atomicAdd(&bhist[tid + 256], lh[tid + 256]);
}

__global__ void __launch_bounds__(512) bscan_kernel(const int* __restrict__ bhist,
                                                    int* __restrict__ bbase,
                                                    int* __restrict__ bcursor, int E) {
    __shared__ int sa[512], sb[512];
    int t = threadIdx.x;
    int v = (t < NBK) ? bhist[t] : 0;
    sa[t] = v;
    __syncthreads();
    int* pa = sa; int* pb = sb;
#pragma unroll
    for (int off = 1; off < 512; off <<= 1) {
        pb[t] = pa[t] + ((t >= off) ? pa[t - off] : 0);
        __syncthreads();
        int* tmp = pa; pa = pb; pb = tmp;
    }
    if (t < NBK) {
        int excl = pa[t] - v;
        bbase[t] = excl;
        bcursor[t] = excl;
    }
    if (t == 0) bbase[NBK] = E;
}

__global__ void __launch_bounds__(256) binscatter_kernel(const int* __restrict__ src,
                                                         const int* __restrict__ dst,
                                                         int* __restrict__ bcursor,
                                                         int2* __restrict__ pairs, int E) {
    __shared__ int2 sp[CHUNK];
    __shared__ unsigned short sbof[CHUNK];
    __shared__ int hist[512];
    __shared__ int scanA[512], scanB[512];
    __shared__ int cur[512];
    __shared__ int gbase[512];
    int tid = threadIdx.x;
    int e0 = blockIdx.x * CHUNK;
    int cnt = min(CHUNK, E - e0);

    int dv[CHUNK / 256], sv[CHUNK / 256];
#pragma unroll
    for (int i = 0; i < CHUNK / 256; i++) {
        int idx = tid + i * 256;
        if (idx < cnt) {
            dv[i] = __builtin_nontemporal_load(&dst[e0 + idx]);
            sv[i] = __builtin_nontemporal_load(&src[e0 + idx]);
        }
    }
    hist[tid] = 0; hist[tid + 256] = 0;
    __syncthreads();
#pragma unroll
    for (int i = 0; i < CHUNK / 256; i++) {
        int idx = tid + i * 256;
        if (idx < cnt) atomicAdd(&hist[dv[i] >> 8], 1);
    }
    __syncthreads();
    scanA[tid] = hist[tid]; scanA[tid + 256] = hist[tid + 256];
    __syncthreads();
    int* pa = scanA; int* pb = scanB;
#pragma unroll
    for (int off = 1; off < 512; off <<= 1) {
        pb[tid] = pa[tid] + ((tid >= off) ? pa[tid - off] : 0);
        int t1 = tid + 256;
        pb[t1] = pa[t1] + ((t1 >= off) ? pa[t1 - off] : 0);
        __syncthreads();
        int* tmp = pa; pa = pb; pb = tmp;
    }
    cur[tid] = pa[tid] - hist[tid];
    cur[tid + 256] = pa[tid + 256] - hist[tid + 256];
    __syncthreads();
#pragma unroll
    for (int i = 0; i < CHUNK / 256; i++) {
        int idx = tid + i * 256;
        if (idx < cnt) {
            int b = dv[i] >> 8;
            int lp = atomicAdd(&cur[b], 1);
            sp[lp] = make_int2(dv[i], sv[i]);
            sbof[lp] = (unsigned short)b;
        }
    }
    {
        int c0 = hist[tid];
        gbase[tid] = c0 ? atomicAdd(&bcursor[tid], c0) : 0;
        int c1 = hist[tid + 256];
        gbase[tid + 256] = c1 ? atomicAdd(&bcursor[tid + 256], c1) : 0;
    }
    __syncthreads();
    for (int i = tid; i < cnt; i += 256) {
        int b = sbof[i];
        int off_in_b = i - (pa[b] - hist[b]);
        pairs[gbase[b] + off_in_b] = sp[i];
    }
}

__global__ void __launch_bounds__(256) bucketsort_kernel(const int2* __restrict__ pairs,
                                                         const int* __restrict__ bbase,
                                                         int* __restrict__ rowptr,
                                                         int* __restrict__ ssrc, int N, int E) {
    __shared__ int hist[256], scanA[256], scanB[256], cur[256];
    int b = blockIdx.x;
    int tid = threadIdx.x;
    int e0 = bbase[b], e1 = bbase[b + 1];
    hist[tid] = 0;
    __syncthreads();
    for (int e = e0 + tid; e < e1; e += 256) {
        int2 p = pairs[e];
        atomicAdd(&hist[p.x & 255], 1);
    }
    __syncthreads();
    scanA[tid] = hist[tid];
    __syncthreads();
    int* pa = scanA; int* pb = scanB;
#pragma unroll
    for (int off = 1; off < 256; off <<= 1) {
        pb[tid] = pa[tid] + ((tid >= off) ? pa[tid - off] : 0);
        __syncthreads();
        int* tmp = pa; pa = pb; pb = tmp;
    }
    int excl = pa[tid] - hist[tid];
    int node = (b << 8) + tid;
    if (node < N) rowptr[node] = e0 + excl;
    if (b == NBK - 1 && tid == 0) rowptr[N] = E;
    cur[tid] = e0 + excl;
    __syncthreads();
    for (int e = e0 + tid; e < e1; e += 256) {
        int2 p = pairs[e];
        int pos = atomicAdd(&cur[p.x & 255], 1);
        ssrc[pos] = p.y;
    }
}

// ---- lin1: LDS-staged x tile, 32 rows/block; writes NORMALIZED fp16 rows + norms ----
__global__ void __launch_bounds__(256) lin1_kernel(
        const float* __restrict__ x, const float* __restrict__ W1,
        const float* __restrict__ b1, _Float16* __restrict__ hnout,
        float* __restrict__ nrmout, int n) {
    __shared__ float sx[32 * F_IN];  // 16 KB
    int tid = threadIdx.x;
    int r0 = blockIdx.x * 32;
    int rows = min(32, n - r0);

    {
        const nf4* xg = (const nf4*)(x + (size_t)r0 * F_IN);
        nf4* sx4 = (nf4*)sx;
        int tot = rows * (F_IN / 4);
        for (int i = tid; i < tot; i += 256) sx4[i] = __builtin_nontemporal_load(&xg[i]);
    }
    __syncthreads();

    int wave = tid >> 6, lane = tid & 63;
    int rbase = wave * 8;
    float bl = b1[lane];
    float acc[8];
#pragma unroll
    for (int j = 0; j < 8; j++) acc[j] = bl;

    const float4* sx4 = (const float4*)sx;
#pragma unroll 2
    for (int k = 0; k < F_IN; k += 4) {
        float w0 = W1[(k + 0) * H_DIM + lane];
        float w1 = W1[(k + 1) * H_DIM + lane];
        float w2 = W1[(k + 2) * H_DIM + lane];
        float w3 = W1[(k + 3) * H_DIM + lane];
#pragma unroll
        for (int j = 0; j < 8; j++) {
            float4 xv = sx4[(rbase + j) * (F_IN / 4) + (k >> 2)];
            acc[j] = fmaf(xv.x, w0, acc[j]);
            acc[j] = fmaf(xv.y, w1, acc[j]);
            acc[j] = fmaf(xv.z, w2, acc[j]);
            acc[j] = fmaf(xv.w, w3, acc[j]);
        }
    }

#pragma unroll
    for (int j = 0; j < 8; j++) {
        int r = rbase + j;
        if (r >= rows) break;
        float a = fmaxf(acc[j], 0.0f);
        float ss = a * a;
#pragma unroll
        for (int k = 1; k < 64; k <<= 1) ss += __shfl_xor(ss, k, 64);
        float nn = fmaxf(sqrtf(ss), 1e-12f);
        hnout[(size_t)(r0 + r) * H_DIM + lane] = (_Float16)(a * (1.0f / nn));
        if (lane == 0) nrmout[r0 + r] = nn;
    }
}

// ---- AGNN layer: wave/dst, 8 lanes/edge; fdot2 logits + packed-fp16 accumulate ----
// Input/output rows are NORMALIZED (hn) with separate norm array:
//   logit = hn_i . hn_j ;  out_i = sum w*nrm_j*hn_j / sum w ;  w = exp(logit)
__global__ void __launch_bounds__(256) agnn_kernel(
        const h8* __restrict__ h, const float* __restrict__ nrm,
        const int* __restrict__ rowptr, const int* __restrict__ ssrc,
        h8* __restrict__ hout, float* __restrict__ nrmout, int n) {
    int wid = (blockIdx.x * blockDim.x + threadIdx.x) >> 6;
    int t = threadIdx.x & 63;
    if (wid >= n) return;
    int g = t >> 3;    // edge group 0..7
    int sub = t & 7;   // feature chunk (8 halves = 16B)

    H8 hd; hd.v = h[(size_t)wid * 8 + sub];
    float ni = nrm[wid];

    // self loop: dself = ||hn_i||^2 (==1 except eps-clamped rows)
    float dself = dot8(hd, hd);
#pragma unroll
    for (int k = 1; k < 8; k <<= 1) dself += __shfl_xor(dself, k, 64);
    float wself = __expf(dself);
    float aself = wself * ni;

    half2t acc2[4];
    float sw;
    if (g == 0) {
        half2t ap = {(_Float16)aself, (_Float16)aself};
#pragma unroll
        for (int j = 0; j < 4; j++) acc2[j] = ap * hd.p[j];
        sw = wself;
    } else {
        half2t z = {(_Float16)0.0f, (_Float16)0.0f};
#pragma unroll
        for (int j = 0; j < 4; j++) acc2[j] = z;
        sw = 0.0f;
    }

    int e = rowptr[wid] + g;
    int end = rowptr[wid + 1];

    // 2 edges per group per iteration
    for (; e + 8 < end; e += 16) {
        int s0 = ssrc[e];
        int s1 = ssrc[e + 8];
        H8 A, B;
        A.v = h[(size_t)s0 * 8 + sub];
        B.v = h[(size_t)s1 * 8 + sub];
        float n0 = nrm[s0];
        float n1 = nrm[s1];
        float d0 = dot8(A, hd);
        float d1 = dot8(B, hd);
#pragma unroll
        for (int k = 1; k < 8; k <<= 1) {
            d0 += __shfl_xor(d0, k, 64);
            d1 += __shfl_xor(d1, k, 64);
        }
        float w0 = __expf(d0);
        float w1 = __expf(d1);
        sw += w0 + w1;
        float a0 = w0 * n0;
        float a1 = w1 * n1;
        half2t a0p = {(_Float16)a0, (_Float16)a0};
        half2t a1p = {(_Float16)a1, (_Float16)a1};
#pragma unroll
        for (int j = 0; j < 4; j++) acc2[j] += a0p * A.p[j] + a1p * B.p[j];  // v_pk_fma_f16
    }
    for (; e < end; e += 8) {
        int s0 = ssrc[e];
        H8 A;
        A.v = h[(size_t)s0 * 8 + sub];
        float n0 = nrm[s0];
        float d0 = dot8(A, hd);
#pragma unroll
        for (int k = 1; k < 8; k <<= 1) d0 += __shfl_xor(d0, k, 64);
        float w0 = __expf(d0);
        sw += w0;
        float a0 = w0 * n0;
        half2t a0p = {(_Float16)a0, (_Float16)a0};
#pragma unroll
        for (int j = 0; j < 4; j++) acc2[j] += a0p * A.p[j];
    }

    // combine the 8 groups (packed halves shuffled as b32)
#pragma unroll
    for (int k = 8; k < 64; k <<= 1) {
#pragma unroll
        for (int j = 0; j < 4; j++) {
            int u = __shfl_xor(__builtin_bit_cast(int, acc2[j]), k, 64);
            acc2[j] += __builtin_bit_cast(half2t, u);
        }
        sw += __shfl_xor(sw, k, 64);
    }

    float inv = 1.0f / sw;
    float o[8];
#pragma unroll
    for (int j = 0; j < 4; j++) {
        o[2 * j] = (float)acc2[j][0] * inv;
        o[2 * j + 1] = (float)acc2[j][1] * inv;
    }
    float ss = 0.0f;
#pragma unroll
    for (int i = 0; i < 8; i++) ss = fmaf(o[i], o[i], ss);
#pragma unroll
    for (int k = 1; k < 8; k <<= 1) ss += __shfl_xor(ss, k, 64);
    float nn = fmaxf(sqrtf(ss), 1e-12f);
    if (g == 0) {
        float r = 1.0f / nn;
        h8 oh;
#pragma unroll
        for (int i = 0; i < 8; i++) oh[i] = (_Float16)(o[i] * r);
        hout[(size_t)wid * 8 + sub] = oh;
    }
    if (t == 0) nrmout[wid] = nn;
}

// ---- lin2 + log_softmax: normalized fp16 input + per-row norm, LDS-staged ----
__global__ void __launch_bounds__(256) lin2_kernel(
        const h8* __restrict__ h, const float* __restrict__ nrm,
        const float* __restrict__ W2, const float* __restrict__ b2,
        float* __restrict__ out, int n) {
    __shared__ h8 sh[32 * 8];  // 4 KB
    __shared__ float snrm[32];
    int tid = threadIdx.x;
    int r0 = blockIdx.x * 32;
    int rows = min(32, n - r0);

    {
        const uint4* hg = (const uint4*)(h + (size_t)r0 * 8);
        uint4* sh4 = (uint4*)sh;
        int tot = rows * 8;
        for (int i = tid; i < tot; i += 256) sh4[i] = hg[i];
        if (tid < rows) snrm[tid] = nrm[r0 + tid];
    }
    __syncthreads();

    int wave = tid >> 6, lane = tid & 63;
    int rbase = wave * 8;

    float acc[8];
    if (lane < C_OUT) {
#pragma unroll
        for (int j = 0; j < 8; j++) acc[j] = 0.0f;
#pragma unroll 2
        for (int k = 0; k < H_DIM; k += 8) {
            float w[8];
#pragma unroll
            for (int i = 0; i < 8; i++) w[i] = W2[(k + i) * C_OUT + lane];
#pragma unroll
            for (int j = 0; j < 8; j++) {
                h8 hv = sh[(rbase + j) * 8 + (k >> 3)];
#pragma unroll
                for (int i = 0; i < 8; i++) acc[j] = fmaf((float)hv[i], w[i], acc[j]);
            }
        }
        float bl = b2[lane];
#pragma unroll
        for (int j = 0; j < 8; j++) acc[j] = fmaf(snrm[rbase + j], acc[j], bl);  // un-normalize
    } else {
#pragma unroll
        for (int j = 0; j < 8; j++) acc[j] = -INFINITY;
    }

#pragma unroll
    for (int j = 0; j < 8; j++) {
        int r = rbase + j;
        if (r >= rows) break;
        float m = acc[j];
#pragma unroll
        for (int k = 1; k < 64; k <<= 1) m = fmaxf(m, __shfl_xor(m, k, 64));
        float e = (lane < C_OUT) ? __expf(acc[j] - m) : 0.0f;
        float s = e;
#pragma unroll
        for (int k = 1; k < 64; k <<= 1) s += __shfl_xor(s, k, 64);
        if (lane < C_OUT) out[(size_t)(r0 + r) * C_OUT + lane] = acc[j] - m - logf(s);
    }
}

// ---------------- launch ----------------

extern "C" void kernel_launch(void* const* d_in, const int* in_sizes, int n_in,
                              void* d_out, int out_size, void* d_ws, size_t ws_size,
                              hipStream_t stream) {
    const float* x = (const float*)d_in[0];
    const float* W1 = (const float*)d_in[1];
    const float* b1 = (const float*)d_in[2];
    const float* W2 = (const float*)d_in[3];
    const float* b2 = (const float*)d_in[4];
    const int* ei = (const int*)d_in[5];

    const int N = in_sizes[0] / F_IN;      // 100000
    const int E = in_sizes[5] / 2;         // 1600000
    const int* src = ei;
    const int* dst = ei + E;

    char* w = (char*)d_ws;
    auto carve = [&](size_t bytes) {
        char* p = w;
        w += (bytes + 255) & ~(size_t)255;
        return p;
    };
    _Float16* g1 = (_Float16*)carve((size_t)N * H_DIM * 2);
    _Float16* g2 = (_Float16*)carve((size_t)N * H_DIM * 2);   // aliased as pairs during CSR build
    float* rn1 = (float*)carve((size_t)N * 4);
    float* rn2 = (float*)carve((size_t)N * 4);
    int* rowptr = (int*)carve((size_t)(N + 1) * 4);
    int* bhist = (int*)carve(512 * 4);
    int* bbase = (int*)carve(512 * 4);
    int* bcursor = (int*)carve(512 * 4);
    int* ssrc = (int*)carve((size_t)E * 4);
    int2* pairs = (int2*)g2;   // 12.8 MB alias: pairs dead before agnn layer 1 writes g2

    // CSR build: two-level LDS counting sort (all writes structurally coalesced)
    (void)hipMemsetAsync(bhist, 0, 512 * 4, stream);
    bhist_kernel<<<512, 256, 0, stream>>>(dst, bhist, E);
    bscan_kernel<<<1, 512, 0, stream>>>(bhist, bbase, bcursor, E);
    binscatter_kernel<<<(E + CHUNK - 1) / CHUNK, 256, 0, stream>>>(src, dst, bcursor, pairs, E);
    bucketsort_kernel<<<NBK, 256, 0, stream>>>(pairs, bbase, rowptr, ssrc, N, E);

    // lin1: normalized fp16 rows + norms
    lin1_kernel<<<(N + 31) / 32, 256, 0, stream>>>(x, W1, b1, g1, rn1, N);

    // 4 AGNN layers, ping-pong on normalized fp16 h
    {
        int blocks = (N * 64 + 255) / 256;
        agnn_kernel<<<blocks, 256, 0, stream>>>((const h8*)g1, rn1, rowptr, ssrc, (h8*)g2, rn2, N);
        agnn_kernel<<<blocks, 256, 0, stream>>>((const h8*)g2, rn2, rowptr, ssrc, (h8*)g1, rn1, N);
        agnn_kernel<<<blocks, 256, 0, stream>>>((const h8*)g1, rn1, rowptr, ssrc, (h8*)g2, rn2, N);
        agnn_kernel<<<blocks, 256, 0, stream>>>((const h8*)g2, rn2, rowptr, ssrc, (h8*)g1, rn1, N);
    }

    // lin2 + log_softmax
    lin2_kernel<<<(N + 31) / 32, 256, 0, stream>>>((const h8*)g1, rn1, W2, b2, (float*)d_out, N);
}

// Round 10
// 404.678 us; speedup vs baseline: 1.1405x; 1.0872x over previous
//
#include <hip/hip_runtime.h>
#include <math.h>

#define F_IN 128
#define H_DIM 64
#define C_OUT 40
#define NBK 391          // ceil(100000/256) coarse buckets, 256 nodes each
#define CHUNK 4096       // edges per binscatter block
#define XPAD 136         // padded LDS half-stride (128 + 8) -> bank spread

typedef _Float16 h8 __attribute__((ext_vector_type(8)));   // 16B = 8 fp16 features
typedef _Float16 half2t __attribute__((ext_vector_type(2)));
typedef float nf4 __attribute__((ext_vector_type(4)));     // native float4 (nt-load-able)
typedef _Float16 f16x8 __attribute__((ext_vector_type(8)));
typedef float f32x4 __attribute__((ext_vector_type(4)));

union H8 {
    h8 v;
    half2t p[4];
};

__device__ __forceinline__ float dot8(const H8& a, const H8& b) {
    float d = __builtin_amdgcn_fdot2(a.p[0], b.p[0], 0.0f, false);
    d = __builtin_amdgcn_fdot2(a.p[1], b.p[1], d, false);
    d = __builtin_amdgcn_fdot2(a.p[2], b.p[2], d, false);
    d = __builtin_amdgcn_fdot2(a.p[3], b.p[3], d, false);
    return d;
}

// ---------------- CSR build: two-level LDS counting sort ----------------

__global__ void __launch_bounds__(256) bhist_kernel(const int* __restrict__ dst,
                                                    int* __restrict__ bhist, int E) {
    __shared__ int lh[512];
    int tid = threadIdx.x;
    lh[tid] = 0; lh[tid + 256] = 0;
    __syncthreads();
    int stride = gridDim.x * 256;
    for (int e = blockIdx.x * 256 + tid; e < E; e += stride) {
        int d = __builtin_nontemporal_load(&dst[e]);
        atomicAdd(&lh[d >> 8], 1);
    }
    __syncthreads();
    if (lh[tid]) atomicAdd(&bhist[tid], lh[tid]);
    if (lh[tid + 256]) atomicAdd(&bhist[tid + 256], lh[tid + 256]);
}

__global__ void __launch_bounds__(512) bscan_kernel(const int* __restrict__ bhist,
                                                    int* __restrict__ bbase,
                                                    int* __restrict__ bcursor, int E) {
    __shared__ int sa[512], sb[512];
    int t = threadIdx.x;
    int v = (t < NBK) ? bhist[t] : 0;
    sa[t] = v;
    __syncthreads();
    int* pa = sa; int* pb = sb;
#pragma unroll
    for (int off = 1; off < 512; off <<= 1) {
        pb[t] = pa[t] + ((t >= off) ? pa[t - off] : 0);
        __syncthreads();
        int* tmp = pa; pa = pb; pb = tmp;
    }
    if (t < NBK) {
        int excl = pa[t] - v;
        bbase[t] = excl;
        bcursor[t] = excl;
    }
    if (t == 0) bbase[NBK] = E;
}

__global__ void __launch_bounds__(256) binscatter_kernel(const int* __restrict__ src,
                                                         const int* __restrict__ dst,
                                                         int* __restrict__ bcursor,
                                                         int2* __restrict__ pairs, int E) {
    __shared__ int2 sp[CHUNK];
    __shared__ unsigned short sbof[CHUNK];
    __shared__ int hist[512];
    __shared__ int scanA[512], scanB[512];
    __shared__ int cur[512];
    __shared__ int gbase[512];
    int tid = threadIdx.x;
    int e0 = blockIdx.x * CHUNK;
    int cnt = min(CHUNK, E - e0);

    int dv[CHUNK / 256], sv[CHUNK / 256];
#pragma unroll
    for (int i = 0; i < CHUNK / 256; i++) {
        int idx = tid + i * 256;
        if (idx < cnt) {
            dv[i] = __builtin_nontemporal_load(&dst[e0 + idx]);
            sv[i] = __builtin_nontemporal_load(&src[e0 + idx]);
        }
    }
    hist[tid] = 0; hist[tid + 256] = 0;
    __syncthreads();
#pragma unroll
    for (int i = 0; i < CHUNK / 256; i++) {
        int idx = tid + i * 256;
        if (idx < cnt) atomicAdd(&hist[dv[i] >> 8], 1);
    }
    __syncthreads();
    scanA[tid] = hist[tid]; scanA[tid + 256] = hist[tid + 256];
    __syncthreads();
    int* pa = scanA; int* pb = scanB;
#pragma unroll
    for (int off = 1; off < 512; off <<= 1) {
        pb[tid] = pa[tid] + ((tid >= off) ? pa[tid - off] : 0);
        int t1 = tid + 256;
        pb[t1] = pa[t1] + ((t1 >= off) ? pa[t1 - off] : 0);
        __syncthreads();
        int* tmp = pa; pa = pb; pb = tmp;
    }
    cur[tid] = pa[tid] - hist[tid];
    cur[tid + 256] = pa[tid + 256] - hist[tid + 256];
    __syncthreads();
#pragma unroll
    for (int i = 0; i < CHUNK / 256; i++) {
        int idx = tid + i * 256;
        if (idx < cnt) {
            int b = dv[i] >> 8;
            int lp = atomicAdd(&cur[b], 1);
            sp[lp] = make_int2(dv[i], sv[i]);
            sbof[lp] = (unsigned short)b;
        }
    }
    {
        int c0 = hist[tid];
        gbase[tid] = c0 ? atomicAdd(&bcursor[tid], c0) : 0;
        int c1 = hist[tid + 256];
        gbase[tid + 256] = c1 ? atomicAdd(&bcursor[tid + 256], c1) : 0;
    }
    __syncthreads();
    for (int i = tid; i < cnt; i += 256) {
        int b = sbof[i];
        int off_in_b = i - (pa[b] - hist[b]);
        pairs[gbase[b] + off_in_b] = sp[i];
    }
}

__global__ void __launch_bounds__(256) bucketsort_kernel(const int2* __restrict__ pairs,
                                                         const int* __restrict__ bbase,
                                                         int* __restrict__ rowptr,
                                                         int* __restrict__ ssrc, int N, int E) {
    __shared__ int hist[256], scanA[256], scanB[256], cur[256];
    int b = blockIdx.x;
    int tid = threadIdx.x;
    int e0 = bbase[b], e1 = bbase[b + 1];
    hist[tid] = 0;
    __syncthreads();
    for (int e = e0 + tid; e < e1; e += 256) {
        int2 p = pairs[e];
        atomicAdd(&hist[p.x & 255], 1);
    }
    __syncthreads();
    scanA[tid] = hist[tid];
    __syncthreads();
    int* pa = scanA; int* pb = scanB;
#pragma unroll
    for (int off = 1; off < 256; off <<= 1) {
        pb[tid] = pa[tid] + ((tid >= off) ? pa[tid - off] : 0);
        __syncthreads();
        int* tmp = pa; pa = pb; pb = tmp;
    }
    int excl = pa[tid] - hist[tid];
    int node = (b << 8) + tid;
    if (node < N) rowptr[node] = e0 + excl;
    if (b == NBK - 1 && tid == 0) rowptr[N] = E;
    cur[tid] = e0 + excl;
    __syncthreads();
    for (int e = e0 + tid; e < e1; e += 256) {
        int2 p = pairs[e];
        int pos = atomicAdd(&cur[p.x & 255], 1);
        ssrc[pos] = p.y;
    }
}

// ---- W1 -> fp16 transposed [col][k] (done once per launch; 16 KB, L2-resident) ----
__global__ void __launch_bounds__(256) cvtw_kernel(const float* __restrict__ W1,
                                                   _Float16* __restrict__ w1t) {
    int t = blockIdx.x * 256 + threadIdx.x;  // t = k*64 + col (coalesced read)
    if (t < F_IN * H_DIM) {
        int k = t >> 6, col = t & 63;
        w1t[col * F_IN + k] = (_Float16)W1[t];
    }
}

// ---- lin1 via MFMA: 64 rows/block, wave = 16 rows x 64 cols; writes normalized fp16 + norms ----
__global__ void __launch_bounds__(256) lin1_kernel(
        const float* __restrict__ x, const _Float16* __restrict__ w1t,
        const float* __restrict__ b1, _Float16* __restrict__ hnout,
        float* __restrict__ nrmout, int n) {
    __shared__ _Float16 sx[64 * XPAD];   // x tile fp16, padded    (17 KB)
    __shared__ _Float16 sw[64 * XPAD];   // W1^T [col][k], padded  (17 KB)
    int tid = threadIdx.x;
    int r0 = blockIdx.x * 64;

    // stage x (fp32 global -> fp16 LDS), zero-fill rows >= n
    for (int ch = tid; ch < 64 * 32; ch += 256) {   // chunks of 4 floats
        int row = ch >> 5, k4 = (ch & 31) << 2;
        float4 xv = make_float4(0.f, 0.f, 0.f, 0.f);
        if (r0 + row < n) xv = *(const float4*)(x + (size_t)(r0 + row) * F_IN + k4);
        _Float16* p = &sx[row * XPAD + k4];
        p[0] = (_Float16)xv.x; p[1] = (_Float16)xv.y;
        p[2] = (_Float16)xv.z; p[3] = (_Float16)xv.w;
    }
    // stage W1^T fp16
    for (int ch = tid; ch < 64 * 16; ch += 256) {   // chunks of 8 halves
        int col = ch >> 4, k8 = (ch & 15) << 3;
        *(uint4*)&sw[col * XPAD + k8] = *(const uint4*)(w1t + col * F_IN + k8);
    }
    __syncthreads();

    int w = tid >> 6, lane = tid & 63;
    int q = lane >> 4, c = lane & 15;

    // A-frags: A[m=c][k=kk*32+q*8+i], rows w*16+c
    f16x8 afrag[4];
#pragma unroll
    for (int kk = 0; kk < 4; kk++)
        afrag[kk] = *(const f16x8*)&sx[(w * 16 + c) * XPAD + kk * 32 + q * 8];

    f32x4 acc[4] = {{0.f,0.f,0.f,0.f},{0.f,0.f,0.f,0.f},{0.f,0.f,0.f,0.f},{0.f,0.f,0.f,0.f}};
#pragma unroll
    for (int ct = 0; ct < 4; ct++) {
#pragma unroll
        for (int kk = 0; kk < 4; kk++) {
            f16x8 bfrag = *(const f16x8*)&sw[(ct * 16 + c) * XPAD + kk * 32 + q * 8];
            acc[ct] = __builtin_amdgcn_mfma_f32_16x16x32_f16(afrag[kk], bfrag, acc[ct], 0, 0, 0);
        }
    }

    // epilogue: elem(row_local=q*4+r, col=ct*16+c) = acc[ct][r]; bias + relu + row norm
    float ss[4] = {0.f, 0.f, 0.f, 0.f};
#pragma unroll
    for (int ct = 0; ct < 4; ct++) {
        float bv = b1[ct * 16 + c];
#pragma unroll
        for (int r = 0; r < 4; r++) {
            float v = fmaxf(acc[ct][r] + bv, 0.0f);
            acc[ct][r] = v;
            ss[r] = fmaf(v, v, ss[r]);
        }
    }
#pragma unroll
    for (int k = 1; k < 16; k <<= 1) {
#pragma unroll
        for (int r = 0; r < 4; r++) ss[r] += __shfl_xor(ss[r], k, 64);
    }
    float nn[4], inv[4];
#pragma unroll
    for (int r = 0; r < 4; r++) {
        nn[r] = fmaxf(sqrtf(ss[r]), 1e-12f);
        inv[r] = 1.0f / nn[r];
    }
    // bounce normalized fp16 through LDS (reuse this wave's own sx rows) for coalesced stores
#pragma unroll
    for (int ct = 0; ct < 4; ct++)
#pragma unroll
        for (int r = 0; r < 4; r++)
            sx[(w * 16 + q * 4 + r) * XPAD + ct * 16 + c] = (_Float16)(acc[ct][r] * inv[r]);

    if (c == 0) {
#pragma unroll
        for (int r = 0; r < 4; r++) {
            int row = r0 + w * 16 + q * 4 + r;
            if (row < n) nrmout[row] = nn[r];
        }
    }
#pragma unroll
    for (int it = 0; it < 2; it++) {
        int row = w * 16 + it * 8 + (lane >> 3);
        int k8 = (lane & 7) * 8;
        if (r0 + row < n)
            *(uint4*)(hnout + (size_t)(r0 + row) * H_DIM + k8) =
                *(const uint4*)&sx[row * XPAD + k8];
    }
}

// ---- AGNN layer: wave/dst, 8 lanes/edge; fdot2 logits + packed-fp16 accumulate ----
__global__ void __launch_bounds__(256) agnn_kernel(
        const h8* __restrict__ h, const float* __restrict__ nrm,
        const int* __restrict__ rowptr, const int* __restrict__ ssrc,
        h8* __restrict__ hout, float* __restrict__ nrmout, int n) {
    int wid = (blockIdx.x * blockDim.x + threadIdx.x) >> 6;
    int t = threadIdx.x & 63;
    if (wid >= n) return;
    int g = t >> 3;    // edge group 0..7
    int sub = t & 7;   // feature chunk (8 halves = 16B)

    H8 hd; hd.v = h[(size_t)wid * 8 + sub];
    float ni = nrm[wid];

    float dself = dot8(hd, hd);
#pragma unroll
    for (int k = 1; k < 8; k <<= 1) dself += __shfl_xor(dself, k, 64);
    float wself = __expf(dself);
    float aself = wself * ni;

    half2t acc2[4];
    float sw;
    if (g == 0) {
        half2t ap = {(_Float16)aself, (_Float16)aself};
#pragma unroll
        for (int j = 0; j < 4; j++) acc2[j] = ap * hd.p[j];
        sw = wself;
    } else {
        half2t z = {(_Float16)0.0f, (_Float16)0.0f};
#pragma unroll
        for (int j = 0; j < 4; j++) acc2[j] = z;
        sw = 0.0f;
    }

    int e = rowptr[wid] + g;
    int end = rowptr[wid + 1];

    for (; e + 8 < end; e += 16) {
        int s0 = ssrc[e];
        int s1 = ssrc[e + 8];
        H8 A, B;
        A.v = h[(size_t)s0 * 8 + sub];
        B.v = h[(size_t)s1 * 8 + sub];
        float n0 = nrm[s0];
        float n1 = nrm[s1];
        float d0 = dot8(A, hd);
        float d1 = dot8(B, hd);
#pragma unroll
        for (int k = 1; k < 8; k <<= 1) {
            d0 += __shfl_xor(d0, k, 64);
            d1 += __shfl_xor(d1, k, 64);
        }
        float w0 = __expf(d0);
        float w1 = __expf(d1);
        sw += w0 + w1;
        float a0 = w0 * n0;
        float a1 = w1 * n1;
        half2t a0p = {(_Float16)a0, (_Float16)a0};
        half2t a1p = {(_Float16)a1, (_Float16)a1};
#pragma unroll
        for (int j = 0; j < 4; j++) acc2[j] += a0p * A.p[j] + a1p * B.p[j];
    }
    for (; e < end; e += 8) {
        int s0 = ssrc[e];
        H8 A;
        A.v = h[(size_t)s0 * 8 + sub];
        float n0 = nrm[s0];
        float d0 = dot8(A, hd);
#pragma unroll
        for (int k = 1; k < 8; k <<= 1) d0 += __shfl_xor(d0, k, 64);
        float w0 = __expf(d0);
        sw += w0;
        float a0 = w0 * n0;
        half2t a0p = {(_Float16)a0, (_Float16)a0};
#pragma unroll
        for (int j = 0; j < 4; j++) acc2[j] += a0p * A.p[j];
    }

#pragma unroll
    for (int k = 8; k < 64; k <<= 1) {
#pragma unroll
        for (int j = 0; j < 4; j++) {
            int u = __shfl_xor(__builtin_bit_cast(int, acc2[j]), k, 64);
            acc2[j] += __builtin_bit_cast(half2t, u);
        }
        sw += __shfl_xor(sw, k, 64);
    }

    float inv = 1.0f / sw;
    float o[8];
#pragma unroll
    for (int j = 0; j < 4; j++) {
        o[2 * j] = (float)acc2[j][0] * inv;
        o[2 * j + 1] = (float)acc2[j][1] * inv;
    }
    float ss = 0.0f;
#pragma unroll
    for (int i = 0; i < 8; i++) ss = fmaf(o[i], o[i], ss);
#pragma unroll
    for (int k = 1; k < 8; k <<= 1) ss += __shfl_xor(ss, k, 64);
    float nn = fmaxf(sqrtf(ss), 1e-12f);
    if (g == 0) {
        float r = 1.0f / nn;
        h8 oh;
#pragma unroll
        for (int i = 0; i < 8; i++) oh[i] = (_Float16)(o[i] * r);
        hout[(size_t)wid * 8 + sub] = oh;
    }
    if (t == 0) nrmout[wid] = nn;
}

// ---- lin2 + log_softmax: normalized fp16 input + per-row norm, LDS-staged ----
__global__ void __launch_bounds__(256) lin2_kernel(
        const h8* __restrict__ h, const float* __restrict__ nrm,
        const float* __restrict__ W2, const float* __restrict__ b2,
        float* __restrict__ out, int n) {
    __shared__ h8 sh[32 * 8];  // 4 KB
    __shared__ float snrm[32];
    int tid = threadIdx.x;
    int r0 = blockIdx.x * 32;
    int rows = min(32, n - r0);

    {
        const uint4* hg = (const uint4*)(h + (size_t)r0 * 8);
        uint4* sh4 = (uint4*)sh;
        int tot = rows * 8;
        for (int i = tid; i < tot; i += 256) sh4[i] = hg[i];
        if (tid < rows) snrm[tid] = nrm[r0 + tid];
    }
    __syncthreads();

    int wave = tid >> 6, lane = tid & 63;
    int rbase = wave * 8;

    float acc[8];
    if (lane < C_OUT) {
#pragma unroll
        for (int j = 0; j < 8; j++) acc[j] = 0.0f;
#pragma unroll 2
        for (int k = 0; k < H_DIM; k += 8) {
            float w[8];
#pragma unroll
            for (int i = 0; i < 8; i++) w[i] = W2[(k + i) * C_OUT + lane];
#pragma unroll
            for (int j = 0; j < 8; j++) {
                h8 hv = sh[(rbase + j) * 8 + (k >> 3)];
#pragma unroll
                for (int i = 0; i < 8; i++) acc[j] = fmaf((float)hv[i], w[i], acc[j]);
            }
        }
        float bl = b2[lane];
#pragma unroll
        for (int j = 0; j < 8; j++) acc[j] = fmaf(snrm[rbase + j], acc[j], bl);
    } else {
#pragma unroll
        for (int j = 0; j < 8; j++) acc[j] = -INFINITY;
    }

#pragma unroll
    for (int j = 0; j < 8; j++) {
        int r = rbase + j;
        if (r >= rows) break;
        float m = acc[j];
#pragma unroll
        for (int k = 1; k < 64; k <<= 1) m = fmaxf(m, __shfl_xor(m, k, 64));
        float e = (lane < C_OUT) ? __expf(acc[j] - m) : 0.0f;
        float s = e;
#pragma unroll
        for (int k = 1; k < 64; k <<= 1) s += __shfl_xor(s, k, 64);
        if (lane < C_OUT) out[(size_t)(r0 + r) * C_OUT + lane] = acc[j] - m - logf(s);
    }
}

// ---------------- launch ----------------

extern "C" void kernel_launch(void* const* d_in, const int* in_sizes, int n_in,
                              void* d_out, int out_size, void* d_ws, size_t ws_size,
                              hipStream_t stream) {
    const float* x = (const float*)d_in[0];
    const float* W1 = (const float*)d_in[1];
    const float* b1 = (const float*)d_in[2];
    const float* W2 = (const float*)d_in[3];
    const float* b2 = (const float*)d_in[4];
    const int* ei = (const int*)d_in[5];

    const int N = in_sizes[0] / F_IN;      // 100000
    const int E = in_sizes[5] / 2;         // 1600000
    const int* src = ei;
    const int* dst = ei + E;

    char* w = (char*)d_ws;
    auto carve = [&](size_t bytes) {
        char* p = w;
        w += (bytes + 255) & ~(size_t)255;
        return p;
    };
    _Float16* g1 = (_Float16*)carve((size_t)N * H_DIM * 2);
    _Float16* g2 = (_Float16*)carve((size_t)N * H_DIM * 2);   // aliased as pairs during CSR build
    float* rn1 = (float*)carve((size_t)N * 4);
    float* rn2 = (float*)carve((size_t)N * 4);
    int* rowptr = (int*)carve((size_t)(N + 1) * 4);
    int* bhist = (int*)carve(512 * 4);
    int* bbase = (int*)carve(512 * 4);
    int* bcursor = (int*)carve(512 * 4);
    int* ssrc = (int*)carve((size_t)E * 4);
    _Float16* w1t = (_Float16*)carve((size_t)F_IN * H_DIM * 2);
    int2* pairs = (int2*)g2;   // 12.8 MB alias: pairs dead before agnn layer 1 writes g2

    // CSR build: two-level LDS counting sort (all writes structurally coalesced)
    (void)hipMemsetAsync(bhist, 0, 512 * 4, stream);
    bhist_kernel<<<512, 256, 0, stream>>>(dst, bhist, E);
    bscan_kernel<<<1, 512, 0, stream>>>(bhist, bbase, bcursor, E);
    binscatter_kernel<<<(E + CHUNK - 1) / CHUNK, 256, 0, stream>>>(src, dst, bcursor, pairs, E);
    bucketsort_kernel<<<NBK, 256, 0, stream>>>(pairs, bbase, rowptr, ssrc, N, E);

    // lin1 via MFMA: normalized fp16 rows + norms
    cvtw_kernel<<<(F_IN * H_DIM + 255) / 256, 256, 0, stream>>>(W1, w1t);
    lin1_kernel<<<(N + 63) / 64, 256, 0, stream>>>(x, w1t, b1, g1, rn1, N);

    // 4 AGNN layers, ping-pong on normalized fp16 h
    {
        int blocks = (N * 64 + 255) / 256;
        agnn_kernel<<<blocks, 256, 0, stream>>>((const h8*)g1, rn1, rowptr, ssrc, (h8*)g2, rn2, N);
        agnn_kernel<<<blocks, 256, 0, stream>>>((const h8*)g2, rn2, rowptr, ssrc, (h8*)g1, rn1, N);
        agnn_kernel<<<blocks, 256, 0, stream>>>((const h8*)g1, rn1, rowptr, ssrc, (h8*)g2, rn2, N);
        agnn_kernel<<<blocks, 256, 0, stream>>>((const h8*)g2, rn2, rowptr, ssrc, (h8*)g1, rn1, N);
    }

    // lin2 + log_softmax
    lin2_kernel<<<(N + 31) / 32, 256, 0, stream>>>((const h8*)g1, rn1, W2, b2, (float*)d_out, N);
}

// Round 11
// 387.351 us; speedup vs baseline: 1.1915x; 1.0447x over previous
//
#include <hip/hip_runtime.h>
#include <math.h>

#define F_IN 128
#define H_DIM 64
#define C_OUT 40
#define NBK 391          // ceil(100000/256) coarse buckets, 256 nodes each
#define CHUNK 4096       // edges per binscatter block
#define XPAD 136         // padded LDS half-stride (128 + 8) -> bank spread

typedef _Float16 h8 __attribute__((ext_vector_type(8)));   // 16B = 8 fp16 features
typedef _Float16 half2t __attribute__((ext_vector_type(2)));
typedef float nf4 __attribute__((ext_vector_type(4)));     // native float4 (nt-load-able)
typedef _Float16 f16x8 __attribute__((ext_vector_type(8)));
typedef float f32x4 __attribute__((ext_vector_type(4)));

union H8 {
    h8 v;
    half2t p[4];
};

__device__ __forceinline__ float dot8(const H8& a, const H8& b) {
    float d = __builtin_amdgcn_fdot2(a.p[0], b.p[0], 0.0f, false);
    d = __builtin_amdgcn_fdot2(a.p[1], b.p[1], d, false);
    d = __builtin_amdgcn_fdot2(a.p[2], b.p[2], d, false);
    d = __builtin_amdgcn_fdot2(a.p[3], b.p[3], d, false);
    return d;
}

// ---------------- CSR build: two-level LDS counting sort ----------------
// pairs packed: (dst&255)<<24 | src   (src < 2^17)

__global__ void __launch_bounds__(256) bhist_kernel(const int* __restrict__ dst,
                                                    int* __restrict__ bhist, int E) {
    __shared__ int lh[512];
    int tid = threadIdx.x;
    lh[tid] = 0; lh[tid + 256] = 0;
    __syncthreads();
    int stride = gridDim.x * 256;
    for (int e = blockIdx.x * 256 + tid; e < E; e += stride) {
        int d = __builtin_nontemporal_load(&dst[e]);
        atomicAdd(&lh[d >> 8], 1);
    }
    __syncthreads();
    if (lh[tid]) atomicAdd(&bhist[tid], lh[tid]);
    if (lh[tid + 256]) atomicAdd(&bhist[tid + 256], lh[tid + 256]);
}

__global__ void __launch_bounds__(512) bscan_kernel(const int* __restrict__ bhist,
                                                    int* __restrict__ bbase,
                                                    int* __restrict__ bcursor, int E) {
    __shared__ int sa[512], sb[512];
    int t = threadIdx.x;
    int v = (t < NBK) ? bhist[t] : 0;
    sa[t] = v;
    __syncthreads();
    int* pa = sa; int* pb = sb;
#pragma unroll
    for (int off = 1; off < 512; off <<= 1) {
        pb[t] = pa[t] + ((t >= off) ? pa[t - off] : 0);
        __syncthreads();
        int* tmp = pa; pa = pb; pb = tmp;
    }
    if (t < NBK) {
        int excl = pa[t] - v;
        bbase[t] = excl;
        bcursor[t] = excl;
    }
    if (t == 0) bbase[NBK] = E;
}

__global__ void __launch_bounds__(256) binscatter_kernel(const int* __restrict__ src,
                                                         const int* __restrict__ dst,
                                                         int* __restrict__ bcursor,
                                                         unsigned int* __restrict__ pairs, int E) {
    __shared__ unsigned int sp[CHUNK];
    __shared__ unsigned short sbof[CHUNK];
    __shared__ int hist[512];
    __shared__ int scanA[512], scanB[512];
    __shared__ int cur[512];
    __shared__ int gbase[512];
    int tid = threadIdx.x;
    int e0 = blockIdx.x * CHUNK;
    int cnt = min(CHUNK, E - e0);

    int dv[CHUNK / 256], sv[CHUNK / 256];
#pragma unroll
    for (int i = 0; i < CHUNK / 256; i++) {
        int idx = tid + i * 256;
        if (idx < cnt) {
            dv[i] = __builtin_nontemporal_load(&dst[e0 + idx]);
            sv[i] = __builtin_nontemporal_load(&src[e0 + idx]);
        }
    }
    hist[tid] = 0; hist[tid + 256] = 0;
    __syncthreads();
#pragma unroll
    for (int i = 0; i < CHUNK / 256; i++) {
        int idx = tid + i * 256;
        if (idx < cnt) atomicAdd(&hist[dv[i] >> 8], 1);
    }
    __syncthreads();
    scanA[tid] = hist[tid]; scanA[tid + 256] = hist[tid + 256];
    __syncthreads();
    int* pa = scanA; int* pb = scanB;
#pragma unroll
    for (int off = 1; off < 512; off <<= 1) {
        pb[tid] = pa[tid] + ((tid >= off) ? pa[tid - off] : 0);
        int t1 = tid + 256;
        pb[t1] = pa[t1] + ((t1 >= off) ? pa[t1 - off] : 0);
        __syncthreads();
        int* tmp = pa; pa = pb; pb = tmp;
    }
    cur[tid] = pa[tid] - hist[tid];
    cur[tid + 256] = pa[tid + 256] - hist[tid + 256];
    __syncthreads();
#pragma unroll
    for (int i = 0; i < CHUNK / 256; i++) {
        int idx = tid + i * 256;
        if (idx < cnt) {
            int b = dv[i] >> 8;
            int lp = atomicAdd(&cur[b], 1);
            sp[lp] = ((unsigned int)(dv[i] & 255) << 24) | (unsigned int)sv[i];
            sbof[lp] = (unsigned short)b;
        }
    }
    {
        int c0 = hist[tid];
        gbase[tid] = c0 ? atomicAdd(&bcursor[tid], c0) : 0;
        int c1 = hist[tid + 256];
        gbase[tid + 256] = c1 ? atomicAdd(&bcursor[tid + 256], c1) : 0;
    }
    __syncthreads();
    for (int i = tid; i < cnt; i += 256) {
        int b = sbof[i];
        int off_in_b = i - (pa[b] - hist[b]);
        pairs[gbase[b] + off_in_b] = sp[i];
    }
}

__global__ void __launch_bounds__(256) bucketsort_kernel(const unsigned int* __restrict__ pairs,
                                                         const int* __restrict__ bbase,
                                                         int* __restrict__ rowptr,
                                                         int* __restrict__ ssrc, int N, int E) {
    __shared__ int hist[256], scanA[256], scanB[256], cur[256];
    int b = blockIdx.x;
    int tid = threadIdx.x;
    int e0 = bbase[b], e1 = bbase[b + 1];
    hist[tid] = 0;
    __syncthreads();
    for (int e = e0 + tid; e < e1; e += 256) {
        unsigned int p = pairs[e];
        atomicAdd(&hist[p >> 24], 1);
    }
    __syncthreads();
    scanA[tid] = hist[tid];
    __syncthreads();
    int* pa = scanA; int* pb = scanB;
#pragma unroll
    for (int off = 1; off < 256; off <<= 1) {
        pb[tid] = pa[tid] + ((tid >= off) ? pa[tid - off] : 0);
        __syncthreads();
        int* tmp = pa; pa = pb; pb = tmp;
    }
    int excl = pa[tid] - hist[tid];
    int node = (b << 8) + tid;
    if (node < N) rowptr[node] = e0 + excl;
    if (b == NBK - 1 && tid == 0) rowptr[N] = E;
    cur[tid] = e0 + excl;
    __syncthreads();
    for (int e = e0 + tid; e < e1; e += 256) {
        unsigned int p = pairs[e];
        int pos = atomicAdd(&cur[p >> 24], 1);
        ssrc[pos] = (int)(p & 0x00FFFFFFu);
    }
}

// ---- W1 -> fp16 transposed [col][k] (once per launch; 16 KB, L2-resident) ----
__global__ void __launch_bounds__(256) cvtw_kernel(const float* __restrict__ W1,
                                                   _Float16* __restrict__ w1t) {
    int t = blockIdx.x * 256 + threadIdx.x;
    if (t < F_IN * H_DIM) {
        int k = t >> 6, col = t & 63;
        w1t[col * F_IN + k] = (_Float16)W1[t];
    }
}

// ---- lin1 via MFMA: 64 rows/block; writes normalized fp16 + norms ----
__global__ void __launch_bounds__(256) lin1_kernel(
        const float* __restrict__ x, const _Float16* __restrict__ w1t,
        const float* __restrict__ b1, _Float16* __restrict__ hnout,
        float* __restrict__ nrmout, int n) {
    __shared__ _Float16 sx[64 * XPAD];
    __shared__ _Float16 sw[64 * XPAD];
    int tid = threadIdx.x;
    int r0 = blockIdx.x * 64;

    for (int ch = tid; ch < 64 * 32; ch += 256) {
        int row = ch >> 5, k4 = (ch & 31) << 2;
        float4 xv = make_float4(0.f, 0.f, 0.f, 0.f);
        if (r0 + row < n) xv = *(const float4*)(x + (size_t)(r0 + row) * F_IN + k4);
        _Float16* p = &sx[row * XPAD + k4];
        p[0] = (_Float16)xv.x; p[1] = (_Float16)xv.y;
        p[2] = (_Float16)xv.z; p[3] = (_Float16)xv.w;
    }
    for (int ch = tid; ch < 64 * 16; ch += 256) {
        int col = ch >> 4, k8 = (ch & 15) << 3;
        *(uint4*)&sw[col * XPAD + k8] = *(const uint4*)(w1t + col * F_IN + k8);
    }
    __syncthreads();

    int w = tid >> 6, lane = tid & 63;
    int q = lane >> 4, c = lane & 15;

    f16x8 afrag[4];
#pragma unroll
    for (int kk = 0; kk < 4; kk++)
        afrag[kk] = *(const f16x8*)&sx[(w * 16 + c) * XPAD + kk * 32 + q * 8];

    f32x4 acc[4] = {{0.f,0.f,0.f,0.f},{0.f,0.f,0.f,0.f},{0.f,0.f,0.f,0.f},{0.f,0.f,0.f,0.f}};
#pragma unroll
    for (int ct = 0; ct < 4; ct++) {
#pragma unroll
        for (int kk = 0; kk < 4; kk++) {
            f16x8 bfrag = *(const f16x8*)&sw[(ct * 16 + c) * XPAD + kk * 32 + q * 8];
            acc[ct] = __builtin_amdgcn_mfma_f32_16x16x32_f16(afrag[kk], bfrag, acc[ct], 0, 0, 0);
        }
    }

    float ss[4] = {0.f, 0.f, 0.f, 0.f};
#pragma unroll
    for (int ct = 0; ct < 4; ct++) {
        float bv = b1[ct * 16 + c];
#pragma unroll
        for (int r = 0; r < 4; r++) {
            float v = fmaxf(acc[ct][r] + bv, 0.0f);
            acc[ct][r] = v;
            ss[r] = fmaf(v, v, ss[r]);
        }
    }
#pragma unroll
    for (int k = 1; k < 16; k <<= 1) {
#pragma unroll
        for (int r = 0; r < 4; r++) ss[r] += __shfl_xor(ss[r], k, 64);
    }
    float nn[4], inv[4];
#pragma unroll
    for (int r = 0; r < 4; r++) {
        nn[r] = fmaxf(sqrtf(ss[r]), 1e-12f);
        inv[r] = 1.0f / nn[r];
    }
#pragma unroll
    for (int ct = 0; ct < 4; ct++)
#pragma unroll
        for (int r = 0; r < 4; r++)
            sx[(w * 16 + q * 4 + r) * XPAD + ct * 16 + c] = (_Float16)(acc[ct][r] * inv[r]);

    if (c == 0) {
#pragma unroll
        for (int r = 0; r < 4; r++) {
            int row = r0 + w * 16 + q * 4 + r;
            if (row < n) nrmout[row] = nn[r];
        }
    }
#pragma unroll
    for (int it = 0; it < 2; it++) {
        int row = w * 16 + it * 8 + (lane >> 3);
        int k8 = (lane & 7) * 8;
        if (r0 + row < n)
            *(uint4*)(hnout + (size_t)(r0 + row) * H_DIM + k8) =
                *(const uint4*)&sx[row * XPAD + k8];
    }
}

// ---- AGNN layer: wave/dst, 8 lanes/edge; up to 4 chains of gathers issued up front ----
__global__ void __launch_bounds__(256) agnn_kernel(
        const h8* __restrict__ h, const float* __restrict__ nrm,
        const int* __restrict__ rowptr, const int* __restrict__ ssrc,
        h8* __restrict__ hout, float* __restrict__ nrmout, int n) {
    int wid = (blockIdx.x * blockDim.x + threadIdx.x) >> 6;
    int t = threadIdx.x & 63;
    if (wid >= n) return;
    int g = t >> 3;    // edge group 0..7
    int sub = t & 7;   // feature chunk (8 halves = 16B)

    H8 hd; hd.v = h[(size_t)wid * 8 + sub];
    float ni = nrm[wid];

    int e0 = rowptr[wid];
    int end = rowptr[wid + 1];
    int deg = end - e0;
    int base = e0 + g;

    // ---- batch 0: chains 0,1 (edges g, g+8), exec-masked loads, issued first ----
    bool v0 = base < end;
    bool v1 = base + 8 < end;
    int s0 = 0, s1 = 0;
    if (v0) s0 = ssrc[base];
    if (v1) s1 = ssrc[base + 8];
    H8 A, B;
    A.v = (h8)(_Float16)0; B.v = (h8)(_Float16)0;
    float n0 = 0.f, n1 = 0.f;
    if (v0) { A.v = h[(size_t)s0 * 8 + sub]; n0 = nrm[s0]; }
    if (v1) { B.v = h[(size_t)s1 * 8 + sub]; n1 = nrm[s1]; }

    // ---- batch 1: chains 2,3 (edges g+16, g+24) — wave-uniform gate, loads before compute ----
    bool big = deg > 16;
    H8 C, D;
    C.v = (h8)(_Float16)0; D.v = (h8)(_Float16)0;
    float n2 = 0.f, n3 = 0.f;
    bool v2 = false, v3 = false;
    if (big) {
        v2 = base + 16 < end;
        v3 = base + 24 < end;
        int s2 = 0, s3 = 0;
        if (v2) s2 = ssrc[base + 16];
        if (v3) s3 = ssrc[base + 24];
        if (v2) { C.v = h[(size_t)s2 * 8 + sub]; n2 = nrm[s2]; }
        if (v3) { D.v = h[(size_t)s3 * 8 + sub]; n3 = nrm[s3]; }
    }

    // self loop
    float dself = dot8(hd, hd);
#pragma unroll
    for (int k = 1; k < 8; k <<= 1) dself += __shfl_xor(dself, k, 64);
    float wself = __expf(dself);
    float aself = wself * ni;

    half2t acc2[4];
    float sw;
    if (g == 0) {
        half2t ap = {(_Float16)aself, (_Float16)aself};
#pragma unroll
        for (int j = 0; j < 4; j++) acc2[j] = ap * hd.p[j];
        sw = wself;
    } else {
        half2t z = {(_Float16)0.0f, (_Float16)0.0f};
#pragma unroll
        for (int j = 0; j < 4; j++) acc2[j] = z;
        sw = 0.0f;
    }

    // ---- compute batch 0 ----
    {
        float d0 = dot8(A, hd);
        float d1 = dot8(B, hd);
#pragma unroll
        for (int k = 1; k < 8; k <<= 1) {
            d0 += __shfl_xor(d0, k, 64);
            d1 += __shfl_xor(d1, k, 64);
        }
        float w0 = v0 ? __expf(d0) : 0.0f;
        float w1 = v1 ? __expf(d1) : 0.0f;
        sw += w0 + w1;
        float a0 = w0 * n0;
        float a1 = w1 * n1;
        half2t a0p = {(_Float16)a0, (_Float16)a0};
        half2t a1p = {(_Float16)a1, (_Float16)a1};
#pragma unroll
        for (int j = 0; j < 4; j++) acc2[j] += a0p * A.p[j] + a1p * B.p[j];
    }
    // ---- compute batch 1 ----
    if (big) {
        float d2 = dot8(C, hd);
        float d3 = dot8(D, hd);
#pragma unroll
        for (int k = 1; k < 8; k <<= 1) {
            d2 += __shfl_xor(d2, k, 64);
            d3 += __shfl_xor(d3, k, 64);
        }
        float w2 = v2 ? __expf(d2) : 0.0f;
        float w3 = v3 ? __expf(d3) : 0.0f;
        sw += w2 + w3;
        float a2 = w2 * n2;
        float a3 = w3 * n3;
        half2t a2p = {(_Float16)a2, (_Float16)a2};
        half2t a3p = {(_Float16)a3, (_Float16)a3};
#pragma unroll
        for (int j = 0; j < 4; j++) acc2[j] += a2p * C.p[j] + a3p * D.p[j];
    }

    // ---- rare tail: deg > 32 ----
    for (int e = base + 32; e < end; e += 8) {
        int st = ssrc[e];
        H8 T;
        T.v = h[(size_t)st * 8 + sub];
        float nt = nrm[st];
        float dt = dot8(T, hd);
#pragma unroll
        for (int k = 1; k < 8; k <<= 1) dt += __shfl_xor(dt, k, 64);
        float wt = __expf(dt);
        sw += wt;
        float at = wt * nt;
        half2t atp = {(_Float16)at, (_Float16)at};
#pragma unroll
        for (int j = 0; j < 4; j++) acc2[j] += atp * T.p[j];
    }

    // combine the 8 groups
#pragma unroll
    for (int k = 8; k < 64; k <<= 1) {
#pragma unroll
        for (int j = 0; j < 4; j++) {
            int u = __shfl_xor(__builtin_bit_cast(int, acc2[j]), k, 64);
            acc2[j] += __builtin_bit_cast(half2t, u);
        }
        sw += __shfl_xor(sw, k, 64);
    }

    float inv = 1.0f / sw;
    float o[8];
#pragma unroll
    for (int j = 0; j < 4; j++) {
        o[2 * j] = (float)acc2[j][0] * inv;
        o[2 * j + 1] = (float)acc2[j][1] * inv;
    }
    float ss = 0.0f;
#pragma unroll
    for (int i = 0; i < 8; i++) ss = fmaf(o[i], o[i], ss);
#pragma unroll
    for (int k = 1; k < 8; k <<= 1) ss += __shfl_xor(ss, k, 64);
    float nn = fmaxf(sqrtf(ss), 1e-12f);
    if (g == 0) {
        float r = 1.0f / nn;
        h8 oh;
#pragma unroll
        for (int i = 0; i < 8; i++) oh[i] = (_Float16)(o[i] * r);
        hout[(size_t)wid * 8 + sub] = oh;
    }
    if (t == 0) nrmout[wid] = nn;
}

// ---- lin2 + log_softmax: normalized fp16 input + per-row norm, LDS-staged ----
__global__ void __launch_bounds__(256) lin2_kernel(
        const h8* __restrict__ h, const float* __restrict__ nrm,
        const float* __restrict__ W2, const float* __restrict__ b2,
        float* __restrict__ out, int n) {
    __shared__ h8 sh[32 * 8];
    __shared__ float snrm[32];
    int tid = threadIdx.x;
    int r0 = blockIdx.x * 32;
    int rows = min(32, n - r0);

    {
        const uint4* hg = (const uint4*)(h + (size_t)r0 * 8);
        uint4* sh4 = (uint4*)sh;
        int tot = rows * 8;
        for (int i = tid; i < tot; i += 256) sh4[i] = hg[i];
        if (tid < rows) snrm[tid] = nrm[r0 + tid];
    }
    __syncthreads();

    int wave = tid >> 6, lane = tid & 63;
    int rbase = wave * 8;

    float acc[8];
    if (lane < C_OUT) {
#pragma unroll
        for (int j = 0; j < 8; j++) acc[j] = 0.0f;
#pragma unroll 2
        for (int k = 0; k < H_DIM; k += 8) {
            float w[8];
#pragma unroll
            for (int i = 0; i < 8; i++) w[i] = W2[(k + i) * C_OUT + lane];
#pragma unroll
            for (int j = 0; j < 8; j++) {
                h8 hv = sh[(rbase + j) * 8 + (k >> 3)];
#pragma unroll
                for (int i = 0; i < 8; i++) acc[j] = fmaf((float)hv[i], w[i], acc[j]);
            }
        }
        float bl = b2[lane];
#pragma unroll
        for (int j = 0; j < 8; j++) acc[j] = fmaf(snrm[rbase + j], acc[j], bl);
    } else {
#pragma unroll
        for (int j = 0; j < 8; j++) acc[j] = -INFINITY;
    }

#pragma unroll
    for (int j = 0; j < 8; j++) {
        int r = rbase + j;
        if (r >= rows) break;
        float m = acc[j];
#pragma unroll
        for (int k = 1; k < 64; k <<= 1) m = fmaxf(m, __shfl_xor(m, k, 64));
        float e = (lane < C_OUT) ? __expf(acc[j] - m) : 0.0f;
        float s = e;
#pragma unroll
        for (int k = 1; k < 64; k <<= 1) s += __shfl_xor(s, k, 64);
        if (lane < C_OUT) out[(size_t)(r0 + r) * C_OUT + lane] = acc[j] - m - logf(s);
    }
}

// ---------------- launch ----------------

extern "C" void kernel_launch(void* const* d_in, const int* in_sizes, int n_in,
                              void* d_out, int out_size, void* d_ws, size_t ws_size,
                              hipStream_t stream) {
    const float* x = (const float*)d_in[0];
    const float* W1 = (const float*)d_in[1];
    const float* b1 = (const float*)d_in[2];
    const float* W2 = (const float*)d_in[3];
    const float* b2 = (const float*)d_in[4];
    const int* ei = (const int*)d_in[5];

    const int N = in_sizes[0] / F_IN;      // 100000
    const int E = in_sizes[5] / 2;         // 1600000
    const int* src = ei;
    const int* dst = ei + E;

    char* w = (char*)d_ws;
    auto carve = [&](size_t bytes) {
        char* p = w;
        w += (bytes + 255) & ~(size_t)255;
        return p;
    };
    _Float16* g1 = (_Float16*)carve((size_t)N * H_DIM * 2);
    _Float16* g2 = (_Float16*)carve((size_t)N * H_DIM * 2);   // aliased as pairs during CSR build
    float* rn1 = (float*)carve((size_t)N * 4);
    float* rn2 = (float*)carve((size_t)N * 4);
    int* rowptr = (int*)carve((size_t)(N + 1) * 4);
    int* bhist = (int*)carve(512 * 4);
    int* bbase = (int*)carve(512 * 4);
    int* bcursor = (int*)carve(512 * 4);
    int* ssrc = (int*)carve((size_t)E * 4);
    _Float16* w1t = (_Float16*)carve((size_t)F_IN * H_DIM * 2);
    unsigned int* pairs = (unsigned int*)g2;  // 6.4 MB alias: dead before agnn layer 1 writes g2

    // CSR build: two-level LDS counting sort (all writes structurally coalesced)
    (void)hipMemsetAsync(bhist, 0, 512 * 4, stream);
    bhist_kernel<<<512, 256, 0, stream>>>(dst, bhist, E);
    bscan_kernel<<<1, 512, 0, stream>>>(bhist, bbase, bcursor, E);
    binscatter_kernel<<<(E + CHUNK - 1) / CHUNK, 256, 0, stream>>>(src, dst, bcursor, pairs, E);
    bucketsort_kernel<<<NBK, 256, 0, stream>>>(pairs, bbase, rowptr, ssrc, N, E);

    // lin1 via MFMA: normalized fp16 rows + norms
    cvtw_kernel<<<(F_IN * H_DIM + 255) / 256, 256, 0, stream>>>(W1, w1t);
    lin1_kernel<<<(N + 63) / 64, 256, 0, stream>>>(x, w1t, b1, g1, rn1, N);

    // 4 AGNN layers, ping-pong on normalized fp16 h
    {
        int blocks = (N * 64 + 255) / 256;
        agnn_kernel<<<blocks, 256, 0, stream>>>((const h8*)g1, rn1, rowptr, ssrc, (h8*)g2, rn2, N);
        agnn_kernel<<<blocks, 256, 0, stream>>>((const h8*)g2, rn2, rowptr, ssrc, (h8*)g1, rn1, N);
        agnn_kernel<<<blocks, 256, 0, stream>>>((const h8*)g1, rn1, rowptr, ssrc, (h8*)g2, rn2, N);
        agnn_kernel<<<blocks, 256, 0, stream>>>((const h8*)g2, rn2, rowptr, ssrc, (h8*)g1, rn1, N);
    }

    // lin2 + log_softmax
    lin2_kernel<<<(N + 31) / 32, 256, 0, stream>>>((const h8*)g1, rn1, W2, b2, (float*)d_out, N);
}